// Round 1
// baseline (1027.149 us; speedup 1.0000x reference)
//
#include <hip/hip_runtime.h>
#include <hip/hip_bf16.h>
#include <stdint.h>

// ---------------------------------------------------------------------------
// Problem constants
// ---------------------------------------------------------------------------
#define N_NODES 50000
#define F_IN    500
#define KP      512          // padded K for GEMM1
#define H_DIM   256
#define E_EDGES 800000
#define R_VIEWS 3
#define ELL_CAP 64

// RNG variant: 0 = partitionable (bits = y0^y1, foldlike split)  [primary]
//              1 = partitionable, bits = y0
//              2 = partitionable, bits = y1
//              3 = legacy/original (split-half pairing, original split)
#define RNG_VARIANT 0

typedef __attribute__((ext_vector_type(8))) short  short8;
typedef __attribute__((ext_vector_type(4))) float  float4v;

// ---------------------------------------------------------------------------
// Threefry-2x32 (JAX-compatible, 20 rounds)
// ---------------------------------------------------------------------------
__host__ __device__ __forceinline__ void tf2x32(uint32_t k0, uint32_t k1,
                                                uint32_t x0, uint32_t x1,
                                                uint32_t& o0, uint32_t& o1) {
  uint32_t ks2 = k0 ^ k1 ^ 0x1BD11BDAu;
#define TF_ROT(x, r) (((x) << (r)) | ((x) >> (32 - (r))))
#define TF_RG(a,b,c,d)                                   \
  x0 += x1; x1 = TF_ROT(x1, a); x1 ^= x0;                \
  x0 += x1; x1 = TF_ROT(x1, b); x1 ^= x0;                \
  x0 += x1; x1 = TF_ROT(x1, c); x1 ^= x0;                \
  x0 += x1; x1 = TF_ROT(x1, d); x1 ^= x0;
  x0 += k0;  x1 += k1;
  TF_RG(13,15,26,6)   x0 += k1;  x1 += ks2 + 1u;
  TF_RG(17,29,16,24)  x0 += ks2; x1 += k0  + 2u;
  TF_RG(13,15,26,6)   x0 += k0;  x1 += k1  + 3u;
  TF_RG(17,29,16,24)  x0 += k1;  x1 += ks2 + 4u;
  TF_RG(13,15,26,6)   x0 += ks2; x1 += k0  + 5u;
  o0 = x0; o1 = x1;
#undef TF_RG
#undef TF_ROT
}

// keep-probability test: u(bits) < 0.8  (bit-exact JAX uniform)
__device__ __forceinline__ bool keep_mask(uint32_t ka, uint32_t kb,
                                          uint32_t t, uint32_t half) {
  uint32_t y0, y1, bits;
#if RNG_VARIANT == 0
  tf2x32(ka, kb, 0u, t, y0, y1); bits = y0 ^ y1;
#elif RNG_VARIANT == 1
  tf2x32(ka, kb, 0u, t, y0, y1); bits = y0;
#elif RNG_VARIANT == 2
  tf2x32(ka, kb, 0u, t, y0, y1); bits = y1;
#else
  if (t < half) { tf2x32(ka, kb, t, t + half, y0, y1); bits = y0; }
  else          { tf2x32(ka, kb, t - half, t, y0, y1); bits = y1; }
#endif
  float u = __uint_as_float((bits >> 9) | 0x3f800000u) - 1.0f;
  return u < 0.8f;
}

__device__ __forceinline__ short f2bf(float f) {   // f32 -> bf16 RNE
  uint32_t u = __float_as_uint(f);
  uint32_t r = (u + 0x7fffu + ((u >> 16) & 1u)) >> 16;
  return (short)r;
}
__device__ __forceinline__ float bf2f(short s) {
  return __uint_as_float(((uint32_t)(unsigned short)s) << 16);
}

// ---------------------------------------------------------------------------
// Weight prep: W1[500][256] -> W1t bf16 [256][512] (K-major, zero pad)
//              W2[256][256] -> W2t bf16 [256][256]
// ---------------------------------------------------------------------------
__global__ void prep_w_kernel(const float* __restrict__ W1,
                              const float* __restrict__ W2,
                              short* __restrict__ W1t,
                              short* __restrict__ W2t) {
  int idx = blockIdx.x * 256 + threadIdx.x;
  if (idx < 256 * KP) {
    int n = idx >> 9, k = idx & (KP - 1);
    W1t[idx] = (k < F_IN) ? f2bf(W1[k * H_DIM + n]) : (short)0;
  } else {
    int j = idx - 256 * KP;
    if (j < 256 * 256) {
      int n = j >> 8, k = j & 255;
      W2t[j] = f2bf(W2[k * H_DIM + n]);
    }
  }
}

// ---------------------------------------------------------------------------
// dropout1: xd[r][c] = mask ? bf16(seq_a * 1.25) : 0, pad cols 500..511 = 0
// ---------------------------------------------------------------------------
__global__ void dropout1_kernel(const float* __restrict__ x,
                                short* __restrict__ xd,
                                uint32_t ka, uint32_t kb) {
  int r = blockIdx.x;
  int c = threadIdx.x;            // 512 threads
  short out = 0;
  if (c < F_IN) {
    uint32_t flat = (uint32_t)r * F_IN + c;
    if (keep_mask(ka, kb, flat, (uint32_t)(N_NODES * (F_IN / 2))))
      out = f2bf(x[flat] * 1.25f);
  }
  xd[(size_t)r * KP + c] = out;
}

// ---------------------------------------------------------------------------
// dropout2: hp0[t] = mask ? bf16(h_a[t] * 1.25) : 0
// ---------------------------------------------------------------------------
__global__ void dropout2_kernel(const float* __restrict__ ha,
                                short* __restrict__ hp0,
                                uint32_t ka, uint32_t kb) {
  uint32_t t = blockIdx.x * 256 + threadIdx.x;   // < 12.8M
  short out = 0;
  if (keep_mask(ka, kb, t, (uint32_t)(N_NODES * (H_DIM / 2))))
    out = f2bf(ha[t] * 1.25f);
  hp0[t] = out;
}

// ---------------------------------------------------------------------------
// MFMA GEMM: C[M][256] = A[M][LDK](bf16) * Bt[256][LDK](bf16)^T + bias
// MODE 0: relu -> bf16 out ; MODE 1: f32 out
// 128x128 tile, 4 waves (2x2), each wave 64x64 = 4x4 frags of 16x16x32.
// LDS layout is fragment-major: per 16x32 subtile, 64 chunks of 16B indexed
// by lane -> ds_read_b128 at lane*16 is conflict-free, no swizzle needed.
// ---------------------------------------------------------------------------
template <int LDK, int MODE>
__global__ void gemm_mfma(const short* __restrict__ A,
                          const short* __restrict__ Bt,
                          const float* __restrict__ bias,
                          void* __restrict__ outp, int M) {
  constexpr int KSTEPS = LDK / 32;
  __shared__ short smA[8 * 64 * 8];   // 8KB
  __shared__ short smB[8 * 64 * 8];   // 8KB

  const int tid = threadIdx.x;
  const int wv  = tid >> 6;
  const int l   = tid & 63;
  const int tileM = blockIdx.x * 128;
  const int tileN = blockIdx.y * 128;
  const int wm = wv >> 1;   // 0..1 row-half
  const int wn = wv & 1;    // 0..1 col-half

  // staging: thread stages chunks c0=tid, c1=tid+256 of both A and B tiles
  const int c0 = tid, c1 = tid + 256;
  const int s0 = c0 >> 6, l0 = c0 & 63;
  const int s1 = c1 >> 6, l1 = c1 & 63;
  int rowA0 = tileM + s0 * 16 + (l0 & 15); if (rowA0 >= M) rowA0 = M - 1;
  int rowA1 = tileM + s1 * 16 + (l1 & 15); if (rowA1 >= M) rowA1 = M - 1;
  const short* gA0 = A + (size_t)rowA0 * LDK + (l0 >> 4) * 8;
  const short* gA1 = A + (size_t)rowA1 * LDK + (l1 >> 4) * 8;
  const int colB0 = tileN + s0 * 16 + (l0 & 15);
  const int colB1 = tileN + s1 * 16 + (l1 & 15);
  const short* gB0 = Bt + (size_t)colB0 * LDK + (l0 >> 4) * 8;
  const short* gB1 = Bt + (size_t)colB1 * LDK + (l1 >> 4) * 8;

  float4v acc[4][4];
#pragma unroll
  for (int i = 0; i < 4; ++i)
#pragma unroll
    for (int j = 0; j < 4; ++j)
      acc[i][j] = (float4v){0.f, 0.f, 0.f, 0.f};

  short8 ra0 = *(const short8*)gA0;
  short8 ra1 = *(const short8*)gA1;
  short8 rb0 = *(const short8*)gB0;
  short8 rb1 = *(const short8*)gB1;

  for (int ks = 0; ks < KSTEPS; ++ks) {
    __syncthreads();                       // previous compute done
    *(short8*)(smA + c0 * 8) = ra0;
    *(short8*)(smA + c1 * 8) = ra1;
    *(short8*)(smB + c0 * 8) = rb0;
    *(short8*)(smB + c1 * 8) = rb1;
    __syncthreads();
    if (ks + 1 < KSTEPS) {                 // prefetch overlaps MFMA below
      const int off = (ks + 1) * 32;
      ra0 = *(const short8*)(gA0 + off);
      ra1 = *(const short8*)(gA1 + off);
      rb0 = *(const short8*)(gB0 + off);
      rb1 = *(const short8*)(gB1 + off);
    }
    short8 af[4], bfr[4];
#pragma unroll
    for (int f = 0; f < 4; ++f) {
      af[f]  = *(const short8*)(smA + ((wm * 4 + f) * 64 + l) * 8);
      bfr[f] = *(const short8*)(smB + ((wn * 4 + f) * 64 + l) * 8);
    }
#pragma unroll
    for (int i = 0; i < 4; ++i)
#pragma unroll
      for (int j = 0; j < 4; ++j)
        acc[i][j] = __builtin_amdgcn_mfma_f32_16x16x32_bf16(af[i], bfr[j],
                                                            acc[i][j], 0, 0, 0);
  }

  // epilogue: D row=(lane>>4)*4+reg, col=lane&15  [m89-verified layout]
  const int rbase = tileM + wm * 64 + (l >> 4) * 4;
  const int cbase = tileN + wn * 64 + (l & 15);
#pragma unroll
  for (int i = 0; i < 4; ++i) {
#pragma unroll
    for (int j = 0; j < 4; ++j) {
      const int col = cbase + j * 16;
      const float bv = bias[col];
#pragma unroll
      for (int r = 0; r < 4; ++r) {
        const int row = rbase + i * 16 + r;
        if (row < M) {
          float v = acc[i][j][r] + bv;
          if (MODE == 0) {
            v = v > 0.f ? v : 0.f;
            ((short*)outp)[(size_t)row * H_DIM + col] = f2bf(v);
          } else {
            ((float*)outp)[(size_t)row * H_DIM + col] = v;
          }
        }
      }
    }
  }
}

// ---------------------------------------------------------------------------
// ELL build: scatter COO edges into per-(view,row) slots (cap 64)
// ---------------------------------------------------------------------------
__global__ void ell_build_kernel(const int* __restrict__ rows,
                                 const int* __restrict__ cols,
                                 const float* __restrict__ vals,
                                 int* __restrict__ cnt,
                                 int* __restrict__ ecol,
                                 float* __restrict__ evalv) {
  int e = blockIdx.x * 256 + threadIdx.x;
  int g = blockIdx.y;
  if (e >= E_EDGES) return;
  size_t src = (size_t)g * E_EDGES + e;
  int r = rows[src];
  int c = cols[src];
  float v = vals[src];
  int slot = atomicAdd(&cnt[g * N_NODES + r], 1);
  if (slot < ELL_CAP) {
    size_t base = ((size_t)(g * N_NODES + r)) * ELL_CAP + slot;
    ecol[base] = c;
    evalv[base] = v;
  }
}

// ---------------------------------------------------------------------------
// SpMM + fusion: block = one row (256 threads = 256 cols), loop 3 views
// ---------------------------------------------------------------------------
__global__ void spmm_kernel(const short* __restrict__ hp0,
                            const int* __restrict__ cnt,
                            const int* __restrict__ ecol,
                            const float* __restrict__ evalv,
                            float* __restrict__ out_stack,
                            float* __restrict__ out_fusion) {
  const int r = blockIdx.x;
  const int tid = threadIdx.x;
  float fsum = 0.f;
#pragma unroll
  for (int g = 0; g < R_VIEWS; ++g) {
    const int base = g * N_NODES + r;
    int deg = cnt[base];
    deg = deg > ELL_CAP ? ELL_CAP : deg;
    const int* ec = ecol + (size_t)base * ELL_CAP;
    const float* ev = evalv + (size_t)base * ELL_CAP;
    float acc = 0.f;
    for (int e = 0; e < deg; ++e) {
      const int c = ec[e];
      const float v = ev[e];
      acc += v * bf2f(hp0[(size_t)c * H_DIM + tid]);
    }
    out_stack[(size_t)g * N_NODES * H_DIM + (size_t)r * H_DIM + tid] = acc;
    fsum += acc;
  }
  out_fusion[(size_t)r * H_DIM + tid] = fsum * (1.f / 3.f);
}

// ---------------------------------------------------------------------------
// launcher
// ---------------------------------------------------------------------------
extern "C" void kernel_launch(void* const* d_in, const int* in_sizes, int n_in,
                              void* d_out, int out_size, void* d_ws, size_t ws_size,
                              hipStream_t stream) {
  const float* seq_a = (const float*)d_in[0];
  const float* vals  = (const float*)d_in[1];
  const float* W1    = (const float*)d_in[2];
  const float* b1    = (const float*)d_in[3];
  const float* W2    = (const float*)d_in[4];
  const float* b2    = (const float*)d_in[5];
  const int*   rows  = (const int*)d_in[6];
  const int*   cols  = (const int*)d_in[7];

  float* out        = (float*)d_out;
  float* out_ha     = out;                                   // 12.8M f32
  float* out_stack  = out + (size_t)N_NODES * H_DIM;         // 38.4M f32
  float* out_fusion = out + (size_t)4 * N_NODES * H_DIM;     // 12.8M f32

  char* ws = (char*)d_ws;
  short* xd    = (short*)(ws);                 // [50000][512] bf16 = 51.2MB
  float* evalv = (float*)(ws);                 // reuse after GEMM1: 38.4MB
  int*   ecol  = (int*)  (ws + 52000000);      // 38.4MB
  short* h     = (short*)(ws + 92000000);      // [50000][256] bf16 = 25.6MB
  short* hp0   = (short*)(ws + 118000000);     // 25.6MB
  short* W1t   = (short*)(ws + 144000000);     // 0.26MB
  short* W2t   = (short*)(ws + 144300000);     // 0.13MB
  int*   cnt   = (int*)  (ws + 144500000);     // 0.6MB

  // --- host-side JAX key derivation: key(42) = (0,42) ---
  uint32_t k0a, k0b, k1a, k1b;
#if RNG_VARIANT == 3
  { uint32_t a0, a1, c0, c1;
    tf2x32(0u, 42u, 0u, 2u, a0, a1);
    tf2x32(0u, 42u, 1u, 3u, c0, c1);
    k0a = a0; k0b = c0; k1a = a1; k1b = c1; }
#else
  tf2x32(0u, 42u, 0u, 0u, k0a, k0b);
  tf2x32(0u, 42u, 0u, 1u, k1a, k1b);
#endif

  hipMemsetAsync(cnt, 0, R_VIEWS * N_NODES * sizeof(int), stream);

  prep_w_kernel<<<(256 * KP + 256 * 256 + 255) / 256, 256, 0, stream>>>(W1, W2, W1t, W2t);

  dropout1_kernel<<<N_NODES, KP, 0, stream>>>(seq_a, xd, k0a, k0b);

  dim3 ggrid((N_NODES + 127) / 128, 2);
  gemm_mfma<KP, 0><<<ggrid, 256, 0, stream>>>(xd, W1t, b1, h, N_NODES);

  ell_build_kernel<<<dim3((E_EDGES + 255) / 256, R_VIEWS), 256, 0, stream>>>(
      rows, cols, vals, cnt, ecol, evalv);

  gemm_mfma<H_DIM, 1><<<ggrid, 256, 0, stream>>>(h, W2t, b2, out_ha, N_NODES);

  dropout2_kernel<<<(N_NODES * H_DIM) / 256, 256, 0, stream>>>(out_ha, hp0, k1a, k1b);

  spmm_kernel<<<N_NODES, H_DIM, 0, stream>>>(hp0, cnt, ecol, evalv,
                                             out_stack, out_fusion);
}

// Round 2
// 824.220 us; speedup vs baseline: 1.2462x; 1.2462x over previous
//
#include <hip/hip_runtime.h>
#include <hip/hip_bf16.h>
#include <stdint.h>

// ---------------------------------------------------------------------------
// Problem constants
// ---------------------------------------------------------------------------
#define N_NODES 50000
#define F_IN    500
#define KP      512          // padded K for GEMM1
#define H_DIM   256
#define E_EDGES 800000
#define R_VIEWS 3
#define ELL_CAP 64

// RNG variant 0 (jax_threefry_partitionable) CONFIRMED by round-1 pass.
typedef __attribute__((ext_vector_type(8))) short  short8;
typedef __attribute__((ext_vector_type(4))) float  float4v;

// ---------------------------------------------------------------------------
// Threefry-2x32 (JAX-compatible, 20 rounds)
// ---------------------------------------------------------------------------
__host__ __device__ __forceinline__ void tf2x32(uint32_t k0, uint32_t k1,
                                                uint32_t x0, uint32_t x1,
                                                uint32_t& o0, uint32_t& o1) {
  uint32_t ks2 = k0 ^ k1 ^ 0x1BD11BDAu;
#define TF_ROT(x, r) (((x) << (r)) | ((x) >> (32 - (r))))
#define TF_RG(a,b,c,d)                                   \
  x0 += x1; x1 = TF_ROT(x1, a); x1 ^= x0;                \
  x0 += x1; x1 = TF_ROT(x1, b); x1 ^= x0;                \
  x0 += x1; x1 = TF_ROT(x1, c); x1 ^= x0;                \
  x0 += x1; x1 = TF_ROT(x1, d); x1 ^= x0;
  x0 += k0;  x1 += k1;
  TF_RG(13,15,26,6)   x0 += k1;  x1 += ks2 + 1u;
  TF_RG(17,29,16,24)  x0 += ks2; x1 += k0  + 2u;
  TF_RG(13,15,26,6)   x0 += k0;  x1 += k1  + 3u;
  TF_RG(17,29,16,24)  x0 += k1;  x1 += ks2 + 4u;
  TF_RG(13,15,26,6)   x0 += ks2; x1 += k0  + 5u;
  o0 = x0; o1 = x1;
#undef TF_RG
#undef TF_ROT
}

// keep-probability test: u(bits) < 0.8 with bits = y0^y1 of TF(key,(0,t))
__device__ __forceinline__ bool keep_mask(uint32_t ka, uint32_t kb, uint32_t t) {
  uint32_t y0, y1;
  tf2x32(ka, kb, 0u, t, y0, y1);
  uint32_t bits = y0 ^ y1;
  float u = __uint_as_float((bits >> 9) | 0x3f800000u) - 1.0f;
  return u < 0.8f;
}

__device__ __forceinline__ short f2bf(float f) {   // f32 -> bf16 RNE
  uint32_t u = __float_as_uint(f);
  uint32_t r = (u + 0x7fffu + ((u >> 16) & 1u)) >> 16;
  return (short)r;
}
__device__ __forceinline__ float bf2f(short s) {
  return __uint_as_float(((uint32_t)(unsigned short)s) << 16);
}

// ---------------------------------------------------------------------------
// Weight prep: W1[500][256] -> W1t bf16 [256][512] (K-major, zero pad)
//              W2[256][256] -> W2t bf16 [256][256]
// ---------------------------------------------------------------------------
__global__ void prep_w_kernel(const float* __restrict__ W1,
                              const float* __restrict__ W2,
                              short* __restrict__ W1t,
                              short* __restrict__ W2t) {
  int idx = blockIdx.x * 256 + threadIdx.x;
  if (idx < 256 * KP) {
    int n = idx >> 9, k = idx & (KP - 1);
    W1t[idx] = (k < F_IN) ? f2bf(W1[k * H_DIM + n]) : (short)0;
  } else {
    int j = idx - 256 * KP;
    if (j < 256 * 256) {
      int n = j >> 8, k = j & 255;
      W2t[j] = f2bf(W2[k * H_DIM + n]);
    }
  }
}

// ---------------------------------------------------------------------------
// dropout1: xd[r][c] = mask ? bf16(seq_a * 1.25) : 0, pad cols 500..511 = 0
// ---------------------------------------------------------------------------
__global__ void dropout1_kernel(const float* __restrict__ x,
                                short* __restrict__ xd,
                                uint32_t ka, uint32_t kb) {
  int r = blockIdx.x;
  int c = threadIdx.x;            // 512 threads
  short out = 0;
  if (c < F_IN) {
    uint32_t flat = (uint32_t)r * F_IN + c;
    if (keep_mask(ka, kb, flat))
      out = f2bf(x[flat] * 1.25f);
  }
  xd[(size_t)r * KP + c] = out;
}

// ---------------------------------------------------------------------------
// MFMA GEMM: C[M][256] = A[M][LDK](bf16) * Bt[256][LDK](bf16)^T + bias
// MODE 0: relu -> bf16 out
// MODE 1: f32 out (nontemporal) + fused dropout -> bf16 hp0
// 128x128 tile, 4 waves (2x2), each wave 64x64 = 4x4 frags of 16x16x32.
// LDS layout fragment-major: ds_read_b128 at lane*16 conflict-free.
// ---------------------------------------------------------------------------
template <int LDK, int MODE>
__global__ void gemm_mfma(const short* __restrict__ A,
                          const short* __restrict__ Bt,
                          const float* __restrict__ bias,
                          void* __restrict__ outp,
                          short* __restrict__ hp0,
                          uint32_t ka, uint32_t kb, int M) {
  constexpr int KSTEPS = LDK / 32;
  __shared__ short smA[8 * 64 * 8];   // 8KB
  __shared__ short smB[8 * 64 * 8];   // 8KB

  const int tid = threadIdx.x;
  const int wv  = tid >> 6;
  const int l   = tid & 63;
  const int tileM = blockIdx.x * 128;
  const int tileN = blockIdx.y * 128;
  const int wm = wv >> 1;
  const int wn = wv & 1;

  const int c0 = tid, c1 = tid + 256;
  const int s0 = c0 >> 6, l0 = c0 & 63;
  const int s1 = c1 >> 6, l1 = c1 & 63;
  int rowA0 = tileM + s0 * 16 + (l0 & 15); if (rowA0 >= M) rowA0 = M - 1;
  int rowA1 = tileM + s1 * 16 + (l1 & 15); if (rowA1 >= M) rowA1 = M - 1;
  const short* gA0 = A + (size_t)rowA0 * LDK + (l0 >> 4) * 8;
  const short* gA1 = A + (size_t)rowA1 * LDK + (l1 >> 4) * 8;
  const int colB0 = tileN + s0 * 16 + (l0 & 15);
  const int colB1 = tileN + s1 * 16 + (l1 & 15);
  const short* gB0 = Bt + (size_t)colB0 * LDK + (l0 >> 4) * 8;
  const short* gB1 = Bt + (size_t)colB1 * LDK + (l1 >> 4) * 8;

  float4v acc[4][4];
#pragma unroll
  for (int i = 0; i < 4; ++i)
#pragma unroll
    for (int j = 0; j < 4; ++j)
      acc[i][j] = (float4v){0.f, 0.f, 0.f, 0.f};

  short8 ra0 = *(const short8*)gA0;
  short8 ra1 = *(const short8*)gA1;
  short8 rb0 = *(const short8*)gB0;
  short8 rb1 = *(const short8*)gB1;

  for (int ks = 0; ks < KSTEPS; ++ks) {
    __syncthreads();
    *(short8*)(smA + c0 * 8) = ra0;
    *(short8*)(smA + c1 * 8) = ra1;
    *(short8*)(smB + c0 * 8) = rb0;
    *(short8*)(smB + c1 * 8) = rb1;
    __syncthreads();
    if (ks + 1 < KSTEPS) {
      const int off = (ks + 1) * 32;
      ra0 = *(const short8*)(gA0 + off);
      ra1 = *(const short8*)(gA1 + off);
      rb0 = *(const short8*)(gB0 + off);
      rb1 = *(const short8*)(gB1 + off);
    }
    short8 af[4], bfr[4];
#pragma unroll
    for (int f = 0; f < 4; ++f) {
      af[f]  = *(const short8*)(smA + ((wm * 4 + f) * 64 + l) * 8);
      bfr[f] = *(const short8*)(smB + ((wn * 4 + f) * 64 + l) * 8);
    }
#pragma unroll
    for (int i = 0; i < 4; ++i)
#pragma unroll
      for (int j = 0; j < 4; ++j)
        acc[i][j] = __builtin_amdgcn_mfma_f32_16x16x32_bf16(af[i], bfr[j],
                                                            acc[i][j], 0, 0, 0);
  }

  // epilogue: D row=(lane>>4)*4+reg, col=lane&15
  const int rbase = tileM + wm * 64 + (l >> 4) * 4;
  const int cbase = tileN + wn * 64 + (l & 15);
#pragma unroll
  for (int i = 0; i < 4; ++i) {
#pragma unroll
    for (int j = 0; j < 4; ++j) {
      const int col = cbase + j * 16;
      const float bv = bias[col];
#pragma unroll
      for (int r = 0; r < 4; ++r) {
        const int row = rbase + i * 16 + r;
        if (row < M) {
          float v = acc[i][j][r] + bv;
          if (MODE == 0) {
            v = v > 0.f ? v : 0.f;
            ((short*)outp)[(size_t)row * H_DIM + col] = f2bf(v);
          } else {
            const uint32_t t = (uint32_t)row * H_DIM + col;
            __builtin_nontemporal_store(v, (float*)outp + t);
            short hd = keep_mask(ka, kb, t) ? f2bf(v * 1.25f) : (short)0;
            hp0[t] = hd;
          }
        }
      }
    }
  }
}

// ---------------------------------------------------------------------------
// ELL build: scatter COO edges into per-(view,row) slots, packed int2
// ---------------------------------------------------------------------------
__global__ void ell_build_kernel(const int* __restrict__ rows,
                                 const int* __restrict__ cols,
                                 const float* __restrict__ vals,
                                 int* __restrict__ cnt,
                                 int2* __restrict__ ell) {
  int e = blockIdx.x * 256 + threadIdx.x;
  int g = blockIdx.y;
  if (e >= E_EDGES) return;
  size_t src = (size_t)g * E_EDGES + e;
  int r = rows[src];
  int c = cols[src];
  float v = vals[src];
  int slot = atomicAdd(&cnt[g * N_NODES + r], 1);
  if (slot < ELL_CAP) {
    ell[((size_t)(g * N_NODES + r)) * ELL_CAP + slot] =
        make_int2(c, __float_as_int(v));
  }
}

// ---------------------------------------------------------------------------
// SpMM + fusion: block = one row (256 threads = 256 cols), loop 3 views.
// 4-way unrolled edge loop (independent accumulators -> latency hiding),
// nontemporal output stores (keep hp0/ELL resident in L2/L3).
// ---------------------------------------------------------------------------
__global__ void spmm_kernel(const short* __restrict__ hp0,
                            const int* __restrict__ cnt,
                            const int2* __restrict__ ell,
                            float* __restrict__ out_stack,
                            float* __restrict__ out_fusion) {
  const int r = blockIdx.x;
  const int tid = threadIdx.x;
  float fsum = 0.f;
#pragma unroll
  for (int g = 0; g < R_VIEWS; ++g) {
    const int base = g * N_NODES + r;
    int deg = cnt[base];
    if (deg > ELL_CAP) deg = ELL_CAP;
    const int2* ep = ell + (size_t)base * ELL_CAP;
    float a0 = 0.f, a1 = 0.f, a2 = 0.f, a3 = 0.f;
    int e = 0;
    for (; e + 4 <= deg; e += 4) {
      const int2 e0 = ep[e + 0];
      const int2 e1 = ep[e + 1];
      const int2 e2 = ep[e + 2];
      const int2 e3 = ep[e + 3];
      const float h0 = bf2f(hp0[(size_t)e0.x * H_DIM + tid]);
      const float h1 = bf2f(hp0[(size_t)e1.x * H_DIM + tid]);
      const float h2 = bf2f(hp0[(size_t)e2.x * H_DIM + tid]);
      const float h3 = bf2f(hp0[(size_t)e3.x * H_DIM + tid]);
      a0 = fmaf(__int_as_float(e0.y), h0, a0);
      a1 = fmaf(__int_as_float(e1.y), h1, a1);
      a2 = fmaf(__int_as_float(e2.y), h2, a2);
      a3 = fmaf(__int_as_float(e3.y), h3, a3);
    }
    for (; e < deg; ++e) {
      const int2 ee = ep[e];
      a0 = fmaf(__int_as_float(ee.y),
                bf2f(hp0[(size_t)ee.x * H_DIM + tid]), a0);
    }
    const float acc = (a0 + a1) + (a2 + a3);
    __builtin_nontemporal_store(
        acc, out_stack + (size_t)g * N_NODES * H_DIM + (size_t)r * H_DIM + tid);
    fsum += acc;
  }
  __builtin_nontemporal_store(fsum * (1.f / 3.f),
                              out_fusion + (size_t)r * H_DIM + tid);
}

// ---------------------------------------------------------------------------
// launcher
// ---------------------------------------------------------------------------
extern "C" void kernel_launch(void* const* d_in, const int* in_sizes, int n_in,
                              void* d_out, int out_size, void* d_ws, size_t ws_size,
                              hipStream_t stream) {
  const float* seq_a = (const float*)d_in[0];
  const float* vals  = (const float*)d_in[1];
  const float* W1    = (const float*)d_in[2];
  const float* b1    = (const float*)d_in[3];
  const float* W2    = (const float*)d_in[4];
  const float* b2    = (const float*)d_in[5];
  const int*   rows  = (const int*)d_in[6];
  const int*   cols  = (const int*)d_in[7];

  float* out        = (float*)d_out;
  float* out_ha     = out;                                   // 12.8M f32
  float* out_stack  = out + (size_t)N_NODES * H_DIM;         // 38.4M f32
  float* out_fusion = out + (size_t)4 * N_NODES * H_DIM;     // 12.8M f32

  char* ws = (char*)d_ws;
  // xd lives in [0, 51.2MB); ELL overlays [0, 76.8MB) AFTER gemm1 consumed xd
  short* xd    = (short*)(ws);                 // [50000][512] bf16 = 51.2MB
  int2*  ell   = (int2*) (ws);                 // 3*50000*64*8B   = 76.8MB
  short* h     = (short*)(ws + 80000000);      // 25.6MB
  short* hp0   = (short*)(ws + 106000000);     // 25.6MB
  short* W1t   = (short*)(ws + 132000000);     // 0.26MB
  short* W2t   = (short*)(ws + 132600000);     // 0.13MB
  int*   cnt   = (int*)  (ws + 133000000);     // 0.6MB

  // host-side JAX key derivation: key(42) -> fold-like split
  uint32_t k0a, k0b, k1a, k1b;
  tf2x32(0u, 42u, 0u, 0u, k0a, k0b);
  tf2x32(0u, 42u, 0u, 1u, k1a, k1b);

  hipMemsetAsync(cnt, 0, R_VIEWS * N_NODES * sizeof(int), stream);

  prep_w_kernel<<<(256 * KP + 256 * 256 + 255) / 256, 256, 0, stream>>>(W1, W2, W1t, W2t);

  dropout1_kernel<<<N_NODES, KP, 0, stream>>>(seq_a, xd, k0a, k0b);

  dim3 ggrid((N_NODES + 127) / 128, 2);
  gemm_mfma<KP, 0><<<ggrid, 256, 0, stream>>>(xd, W1t, b1, h, nullptr, 0u, 0u, N_NODES);

  ell_build_kernel<<<dim3((E_EDGES + 255) / 256, R_VIEWS), 256, 0, stream>>>(
      rows, cols, vals, cnt, ell);

  gemm_mfma<H_DIM, 1><<<ggrid, 256, 0, stream>>>(h, W2t, b2, out_ha, hp0,
                                                 k1a, k1b, N_NODES);

  spmm_kernel<<<N_NODES, H_DIM, 0, stream>>>(hp0, cnt, ell,
                                             out_stack, out_fusion);
}